// Round 5
// baseline (367.022 us; speedup 1.0000x reference)
//
#include <hip/hip_runtime.h>
#include <hip/hip_bf16.h>

#define N_NODES 50000
#define SEQ 12
#define CH 128
#define BS 4
#define TILE 64
#define NTILES ((N_NODES + TILE - 1) / TILE)   // 782
#define QCH 32             // gathered/output channels per slice-block (quarter)
#define PAD_Q 36           // spiral row stride (floats) for 32-ch slice
#define PAD_ROW 132        // fallback kernel row stride

// quarter-slice gather geometry: per wave 16 nodes, chunks of 4 nodes
#define CNODES 4
#define NCHUNK 4
#define CHUNK_SHORTS (CNODES * SEQ * QCH)    // 1536 bf16 = 3 KB = 3 x 1KB instrs
#define CHUNK_INSTR ((CHUNK_SHORTS * 2) / 1024)  // 3

typedef short bf16x8 __attribute__((ext_vector_type(8)));
typedef float f32x4 __attribute__((ext_vector_type(4)));

__device__ __forceinline__ float bflo(unsigned int u) { return __uint_as_float(u << 16); }
__device__ __forceinline__ float bfhi(unsigned int u) { return __uint_as_float(u & 0xFFFF0000u); }

// Async global->LDS, 16B/lane. Global src per-lane, LDS dst = uniform base + lane*16.
__device__ __forceinline__ void gload_lds16b(const unsigned short* g, unsigned short* l) {
    __builtin_amdgcn_global_load_lds(
        (const __attribute__((address_space(1))) void*)g,
        (__attribute__((address_space(3))) void*)l,
        16, 0, 0);
}
__device__ __forceinline__ void gload_lds16f(const float* g, float* l) {
    __builtin_amdgcn_global_load_lds(
        (const __attribute__((address_space(1))) void*)g,
        (__attribute__((address_space(3))) void*)l,
        16, 0, 0);
}

// ---------------- Kernel A: fp32 -> bf16 conversion of x ----------------
__global__ __launch_bounds__(256) void convert_kernel(
    const float* __restrict__ x,
    unsigned short* __restrict__ xb)
{
    const size_t i = (size_t)blockIdx.x * 256 + threadIdx.x;   // one thread per 8 elems
    const size_t n8 = (size_t)BS * N_NODES * CH / 8;           // 3,200,000
    if (i < n8) {
        float4 lo = *(const float4*)(x + i * 8);
        float4 hi = *(const float4*)(x + i * 8 + 4);
        union { bf16x8 v; __hip_bfloat16 h[8]; } o;
        o.h[0] = __float2bfloat16(lo.x); o.h[1] = __float2bfloat16(lo.y);
        o.h[2] = __float2bfloat16(lo.z); o.h[3] = __float2bfloat16(lo.w);
        o.h[4] = __float2bfloat16(hi.x); o.h[5] = __float2bfloat16(hi.y);
        o.h[6] = __float2bfloat16(hi.z); o.h[7] = __float2bfloat16(hi.w);
        *(bf16x8*)(xb + i * 8) = o.v;
    }
}

// ---------------- Kernel B: fully-L2-resident quarter-slice gather + MFMA gate ----------------
// 16 groups (batch, quarter). Two time-phases of 8 groups; within a phase each
// group pins to one XCD via (blockIdx & 7): 3.2 MB hot set per XCD L2.
__global__ __launch_bounds__(256, 4) void gated_spiral_quarter(
    const unsigned short* __restrict__ xb,
    const int* __restrict__ indices,
    const float* __restrict__ weight,
    const float* __restrict__ gate_w,
    const float* __restrict__ gate_b,
    float* __restrict__ out)
{
    __shared__ float spiral[TILE * PAD_Q];                 // 9216 B
    __shared__ unsigned short gbuf[4][2][CHUNK_SHORTS];    // 24576 B
    __shared__ int   idx_s[TILE * SEQ];                    // 3072 B
    __shared__ float w_s[TILE * SEQ];                      // 3072 B -> 39936 B, 4 blk/CU

    const int tid  = threadIdx.x;
    const int wave = tid >> 6;
    const int lane = tid & 63;

    const int bx    = blockIdx.x;
    const int phase = bx >= NTILES * 8 ? 1 : 0;
    const int r0    = bx - phase * (NTILES * 8);
    const int g8    = r0 & 7;            // XCD affinity (round-robin heuristic)
    const int tile  = r0 >> 3;
    const int b     = g8 >> 1;
    const int q     = (g8 & 1) | (phase << 1);   // quarter 0..3
    const int node0 = tile * TILE;
    const unsigned short* xbb = xb + (size_t)b * N_NODES * CH;

    // ---- Phase 0 (wave-local): stage this wave's 16 nodes' indices + weights ----
    const int sbase = wave * 16 * SEQ;   // 192 entries/wave
    #pragma unroll
    for (int k3 = 0; k3 < 3; ++k3) {
        const int k = k3 * 64 + lane;
        int node = node0 + wave * 16 + k / SEQ;
        if (node >= N_NODES) node = N_NODES - 1;
        int t = __builtin_nontemporal_load(indices + (size_t)node * SEQ + (k % SEQ));
        t = t < 0 ? 0 : (t >= N_NODES ? N_NODES - 1 : t);
        idx_s[sbase + k] = t;
        w_s[sbase + k]   = __builtin_nontemporal_load(weight + (size_t)node * SEQ + (k % SEQ));
    }
    // same-wave LDS producer/consumer: ordered via lgkmcnt by the compiler

    // ---- Phase 1: per-wave double-buffered async quarter-slice gather + reduce ----
    {
        const int* idxw = idx_s + sbase;
        const float* ww = w_s + sbase;
        unsigned short* gw0 = &gbuf[wave][0][0];
        const int lrow = lane >> 2;          // 16 rows (64B each) per 1KB instr
        const int lco  = (lane & 3) * 8;     // bf16 elems within a 64B row slice

        // prologue: issue chunks 0 and 1 (3 x 1KB each)
        #pragma unroll
        for (int c0 = 0; c0 < 2; ++c0) {
            unsigned short* dst = gw0 + c0 * CHUNK_SHORTS;
            #pragma unroll
            for (int i = 0; i < CHUNK_INSTR; ++i) {
                const int rs = i * 16 + lrow;      // 0..47 = s*4 + n
                const int s = rs >> 2, n = rs & 3;
                const int row = idxw[(c0 * CNODES + n) * SEQ + s];
                gload_lds16b(xbb + (size_t)row * CH + q * QCH + lco, dst + i * 512);
            }
        }

        #pragma unroll
        for (int c = 0; c < NCHUNK; ++c) {
            if (c < NCHUNK - 1) asm volatile("s_waitcnt vmcnt(3)" ::: "memory");
            else                asm volatile("s_waitcnt vmcnt(0)" ::: "memory");
            __builtin_amdgcn_sched_barrier(0);

            unsigned short* bufp = gw0 + (c & 1) * CHUNK_SHORTS;
            const int nr = lane >> 4;            // node within chunk (0..3)
            const int cp = lane & 15;            // ch-pair (2 bf16) this lane owns
            const float* wp = ww + (c * CNODES + nr) * SEQ;
            float a0 = 0.f, a1 = 0.f;
            #pragma unroll
            for (int s = 0; s < SEQ; ++s) {
                const unsigned int u = *(const unsigned int*)(bufp + (s * 4 + nr) * QCH + cp * 2);
                const float ws = wp[s];
                a0 += ws * bflo(u); a1 += ws * bfhi(u);
            }
            const int r = wave * 16 + c * CNODES + nr;
            *(float2*)(spiral + r * PAD_Q + cp * 2) = make_float2(a0, a1);

            if (c + 2 < NCHUNK) {
                // drain ds_reads of this buffer before async loads overwrite it
                asm volatile("s_waitcnt lgkmcnt(0)" ::: "memory");
                __builtin_amdgcn_sched_barrier(0);
                #pragma unroll
                for (int i = 0; i < CHUNK_INSTR; ++i) {
                    const int rs = i * 16 + lrow;
                    const int s = rs >> 2, n = rs & 3;
                    const int row = idxw[((c + 2) * CNODES + n) * SEQ + s];
                    gload_lds16b(xbb + (size_t)row * CH + q * QCH + lco, bufp + i * 512);
                }
            }
        }
    }
    // no __syncthreads anywhere: all phases wave-local

    // ---- Phase 2: gate GEMM (sliced D: 16 nodes x 32 out-ch per wave) ----
    {
        const int m = lane & 15;
        const int quad = lane >> 4;

        int arow_node = node0 + wave * 16 + m;
        if (arow_node >= N_NODES) arow_node = N_NODES - 1;
        const unsigned short* ap = xbb + (size_t)arow_node * CH + quad * 8;

        bf16x8 afrag[4];
        #pragma unroll
        for (int kk = 0; kk < 4; ++kk)
            afrag[kk] = __builtin_nontemporal_load((const bf16x8*)(ap + kk * 32));

        float gbv[2];
        #pragma unroll
        for (int t = 0; t < 2; ++t)
            gbv[t] = gate_b[q * QCH + t * 16 + m];

        #pragma unroll
        for (int t = 0; t < 2; ++t) {
            f32x4 c = {0.f, 0.f, 0.f, 0.f};
            const float* bp = gate_w + (size_t)(q * QCH + t * 16 + m) * CH + quad * 8;
            #pragma unroll
            for (int kk = 0; kk < 4; ++kk) {
                float4 lo = *(const float4*)(bp + kk * 32);
                float4 hi = *(const float4*)(bp + kk * 32 + 4);
                union { bf16x8 v; __hip_bfloat16 h[8]; } bf;
                bf.h[0] = __float2bfloat16(lo.x); bf.h[1] = __float2bfloat16(lo.y);
                bf.h[2] = __float2bfloat16(lo.z); bf.h[3] = __float2bfloat16(lo.w);
                bf.h[4] = __float2bfloat16(hi.x); bf.h[5] = __float2bfloat16(hi.y);
                bf.h[6] = __float2bfloat16(hi.z); bf.h[7] = __float2bfloat16(hi.w);
                c = __builtin_amdgcn_mfma_f32_16x16x32_bf16(afrag[kk], bf.v, c, 0, 0, 0);
            }
            #pragma unroll
            for (int reg = 0; reg < 4; ++reg) {
                const int r = wave * 16 + quad * 4 + reg;
                const int col = t * 16 + m;                    // out-ch within slice
                const float sp = spiral[r * PAD_Q + col];
                spiral[r * PAD_Q + col] = sp * (c[reg] + gbv[t]);
            }
        }
    }

    // ---- Phase 3: wave-local coalesced slice store (nontemporal) ----
    {
        #pragma unroll
        for (int p = 0; p < 2; ++p) {
            const int seg = p * 64 + lane;        // 128 float4-segments per wave
            const int r = seg >> 3;               // 0..15
            const int i8 = seg & 7;               // float4 index within 32-ch slice
            const int node = node0 + wave * 16 + r;
            if (node < N_NODES) {
                const float* sp = spiral + (wave * 16 + r) * PAD_Q + i8 * 4;
                f32x4 v = { sp[0], sp[1], sp[2], sp[3] };
                __builtin_nontemporal_store(v,
                    (f32x4*)(out + ((size_t)b * N_NODES + node) * CH + q * QCH + i8 * 4));
            }
        }
    }
}

// ---------------- Fallback: proven round-3 fp32 async kernel (ws too small) ----------------
#define NODES_PER_WAVE 16
#define FCHUNK_NODES 2
#define FCHUNK_FLOATS (FCHUNK_NODES * SEQ * CH)  // 3072 floats = 12 KB
#define FNCHUNK (NODES_PER_WAVE / FCHUNK_NODES)  // 8

__global__ __launch_bounds__(256, 1) void gated_spiral_async(
    const float* __restrict__ x,
    const int* __restrict__ indices,
    const float* __restrict__ weight,
    const float* __restrict__ gate_w,
    const float* __restrict__ gate_b,
    float* __restrict__ out)
{
    __shared__ float spiral[TILE * PAD_ROW];
    __shared__ float gbuf[4][2][FCHUNK_FLOATS];
    __shared__ int   idx_s[TILE * SEQ];
    __shared__ float w_s[TILE * SEQ];

    const int tid  = threadIdx.x;
    const int wave = tid >> 6;
    const int lane = tid & 63;
    const int b    = blockIdx.y;
    const int node0 = blockIdx.x * TILE;
    const float* xb = x + (size_t)b * N_NODES * CH;

    const int sbase = wave * NODES_PER_WAVE * SEQ;
    #pragma unroll
    for (int k3 = 0; k3 < 3; ++k3) {
        const int k = k3 * 64 + lane;
        int node = node0 + wave * NODES_PER_WAVE + k / SEQ;
        if (node >= N_NODES) node = N_NODES - 1;
        int t = indices[(size_t)node * SEQ + (k % SEQ)];
        t = t < 0 ? 0 : (t >= N_NODES ? N_NODES - 1 : t);
        idx_s[sbase + k] = t;
        w_s[sbase + k]   = weight[(size_t)node * SEQ + (k % SEQ)];
    }

    {
        const int n  = lane >> 5;
        const int co = (lane & 31) * 4;
        const int* idxw = idx_s + sbase;
        const float* ww = w_s + sbase;
        float* gb0 = &gbuf[wave][0][0];

        #pragma unroll
        for (int c0 = 0; c0 < 2; ++c0) {
            const int* ix = idxw + c0 * FCHUNK_NODES * SEQ;
            float* dst = gb0 + c0 * FCHUNK_FLOATS;
            #pragma unroll
            for (int s = 0; s < SEQ; ++s) {
                const int row = ix[n * SEQ + s];
                gload_lds16f(xb + (size_t)row * CH + co, dst + s * (FCHUNK_NODES * CH));
            }
        }

        #pragma unroll
        for (int c = 0; c < FNCHUNK; ++c) {
            if (c < FNCHUNK - 1) asm volatile("s_waitcnt vmcnt(12)" ::: "memory");
            else                 asm volatile("s_waitcnt vmcnt(0)"  ::: "memory");
            __builtin_amdgcn_sched_barrier(0);

            float* cur = gb0 + (c & 1) * FCHUNK_FLOATS;
            const float* wp = ww + c * FCHUNK_NODES * SEQ + n * SEQ;
            float a0 = 0.f, a1 = 0.f, a2 = 0.f, a3 = 0.f;
            #pragma unroll
            for (int s = 0; s < SEQ; ++s) {
                const float4 d = *(const float4*)(cur + (s * FCHUNK_NODES + n) * CH + co);
                const float ws = wp[s];
                a0 += ws * d.x; a1 += ws * d.y; a2 += ws * d.z; a3 += ws * d.w;
            }
            const int r = wave * NODES_PER_WAVE + c * FCHUNK_NODES + n;
            *(float4*)(spiral + r * PAD_ROW + co) = make_float4(a0, a1, a2, a3);

            if (c + 2 < FNCHUNK) {
                asm volatile("s_waitcnt lgkmcnt(0)" ::: "memory");
                __builtin_amdgcn_sched_barrier(0);
                const int* ix = idxw + (c + 2) * FCHUNK_NODES * SEQ;
                #pragma unroll
                for (int s = 0; s < SEQ; ++s) {
                    const int row = ix[n * SEQ + s];
                    gload_lds16f(xb + (size_t)row * CH + co, cur + s * (FCHUNK_NODES * CH));
                }
            }
        }
    }

    {
        const int m = lane & 15;
        const int quad = lane >> 4;

        int arow_node = node0 + wave * 16 + m;
        if (arow_node >= N_NODES) arow_node = N_NODES - 1;
        const float* ap = xb + (size_t)arow_node * CH + quad * 8;

        bf16x8 afrag[4];
        #pragma unroll
        for (int kk = 0; kk < 4; ++kk) {
            float4 lo = *(const float4*)(ap + kk * 32);
            float4 hi = *(const float4*)(ap + kk * 32 + 4);
            union { bf16x8 v; __hip_bfloat16 h[8]; } af;
            af.h[0] = __float2bfloat16(lo.x); af.h[1] = __float2bfloat16(lo.y);
            af.h[2] = __float2bfloat16(lo.z); af.h[3] = __float2bfloat16(lo.w);
            af.h[4] = __float2bfloat16(hi.x); af.h[5] = __float2bfloat16(hi.y);
            af.h[6] = __float2bfloat16(hi.z); af.h[7] = __float2bfloat16(hi.w);
            afrag[kk] = af.v;
        }

        float gbv[8];
        #pragma unroll
        for (int t = 0; t < 8; ++t)
            gbv[t] = gate_b[t * 16 + m];

        #pragma unroll
        for (int t = 0; t < 8; ++t) {
            f32x4 c = {0.f, 0.f, 0.f, 0.f};
            const float* bp = gate_w + (size_t)(t * 16 + m) * CH + quad * 8;
            #pragma unroll
            for (int kk = 0; kk < 4; ++kk) {
                float4 lo = *(const float4*)(bp + kk * 32);
                float4 hi = *(const float4*)(bp + kk * 32 + 4);
                union { bf16x8 v; __hip_bfloat16 h[8]; } bf;
                bf.h[0] = __float2bfloat16(lo.x); bf.h[1] = __float2bfloat16(lo.y);
                bf.h[2] = __float2bfloat16(lo.z); bf.h[3] = __float2bfloat16(lo.w);
                bf.h[4] = __float2bfloat16(hi.x); bf.h[5] = __float2bfloat16(hi.y);
                bf.h[6] = __float2bfloat16(hi.z); bf.h[7] = __float2bfloat16(hi.w);
                c = __builtin_amdgcn_mfma_f32_16x16x32_bf16(afrag[kk], bf.v, c, 0, 0, 0);
            }
            #pragma unroll
            for (int reg = 0; reg < 4; ++reg) {
                const int r = wave * 16 + quad * 4 + reg;
                const int col = t * 16 + m;
                const float sp = spiral[r * PAD_ROW + col];
                spiral[r * PAD_ROW + col] = sp * (c[reg] + gbv[t]);
            }
        }
    }

    {
        #pragma unroll
        for (int p = 0; p < 8; ++p) {
            const int seg = p * 64 + lane;
            const int r = seg >> 5;
            const int c4 = (seg & 31) * 4;
            const int node = node0 + wave * 16 + r;
            if (node < N_NODES) {
                const float* sp = spiral + (wave * 16 + r) * PAD_ROW + c4;
                f32x4 v = { sp[0], sp[1], sp[2], sp[3] };
                __builtin_nontemporal_store(v, (f32x4*)(out + ((size_t)b * N_NODES + node) * CH + c4));
            }
        }
    }
}

extern "C" void kernel_launch(void* const* d_in, const int* in_sizes, int n_in,
                              void* d_out, int out_size, void* d_ws, size_t ws_size,
                              hipStream_t stream) {
    const float* x       = (const float*)d_in[0];
    const int*   indices = (const int*)d_in[1];
    const float* weight  = (const float*)d_in[2];
    const float* gate_w  = (const float*)d_in[3];
    const float* gate_b  = (const float*)d_in[4];
    float*       out     = (float*)d_out;

    const size_t x_bf_bytes = (size_t)BS * N_NODES * CH * 2;   // 51,200,000

    if (ws_size >= x_bf_bytes) {
        unsigned short* xbuf = (unsigned short*)d_ws;
        const size_t n8 = (size_t)BS * N_NODES * CH / 8;       // 3,200,000
        convert_kernel<<<dim3((unsigned)((n8 + 255) / 256)), dim3(256), 0, stream>>>(x, xbuf);
        gated_spiral_quarter<<<dim3(NTILES * 16), dim3(256), 0, stream>>>(
            xbuf, indices, weight, gate_w, gate_b, out);
    } else {
        dim3 grid(NTILES, BS);
        gated_spiral_async<<<grid, dim3(256), 0, stream>>>(
            x, indices, weight, gate_w, gate_b, out);
    }
}

// Round 6
// 361.115 us; speedup vs baseline: 1.0164x; 1.0164x over previous
//
#include <hip/hip_runtime.h>
#include <hip/hip_bf16.h>

#define N_NODES 50000
#define SEQ 12
#define CH 128
#define BS 4
#define TILE 64
#define NTILES ((N_NODES + TILE - 1) / TILE)   // 782
#define QCH 32             // gathered/output channels per slice-block (quarter)
#define PAD_Q 36           // spiral row stride (floats) for 32-ch slice
#define PAD_ROW 132        // fallback kernel row stride

// quarter-slice gather geometry: per wave 16 nodes, chunks of 4 nodes
#define CNODES 4
#define NCHUNK 4
#define CHUNK_SHORTS (CNODES * SEQ * QCH)    // 1536 bf16 = 3 KB = 3 x 1KB instrs
#define CHUNK_INSTR ((CHUNK_SHORTS * 2) / 1024)  // 3

typedef short bf16x8 __attribute__((ext_vector_type(8)));
typedef float f32x4 __attribute__((ext_vector_type(4)));

__device__ __forceinline__ float bflo(unsigned int u) { return __uint_as_float(u << 16); }
__device__ __forceinline__ float bfhi(unsigned int u) { return __uint_as_float(u & 0xFFFF0000u); }

// Async global->LDS, 16B/lane. Global src per-lane, LDS dst = uniform base + lane*16.
__device__ __forceinline__ void gload_lds16b(const unsigned short* g, unsigned short* l) {
    __builtin_amdgcn_global_load_lds(
        (const __attribute__((address_space(1))) void*)g,
        (__attribute__((address_space(3))) void*)l,
        16, 0, 0);
}
__device__ __forceinline__ void gload_lds16f(const float* g, float* l) {
    __builtin_amdgcn_global_load_lds(
        (const __attribute__((address_space(1))) void*)g,
        (__attribute__((address_space(3))) void*)l,
        16, 0, 0);
}

// ---------------- Kernel A: fp32 -> bf16 conversion of x ----------------
__global__ __launch_bounds__(256) void convert_kernel(
    const float* __restrict__ x,
    unsigned short* __restrict__ xb)
{
    const size_t i = (size_t)blockIdx.x * 256 + threadIdx.x;   // one thread per 8 elems
    const size_t n8 = (size_t)BS * N_NODES * CH / 8;           // 3,200,000
    if (i < n8) {
        float4 lo = *(const float4*)(x + i * 8);
        float4 hi = *(const float4*)(x + i * 8 + 4);
        union { bf16x8 v; __hip_bfloat16 h[8]; } o;
        o.h[0] = __float2bfloat16(lo.x); o.h[1] = __float2bfloat16(lo.y);
        o.h[2] = __float2bfloat16(lo.z); o.h[3] = __float2bfloat16(lo.w);
        o.h[4] = __float2bfloat16(hi.x); o.h[5] = __float2bfloat16(hi.y);
        o.h[6] = __float2bfloat16(hi.z); o.h[7] = __float2bfloat16(hi.w);
        *(bf16x8*)(xb + i * 8) = o.v;
    }
}

// ---------------- Kernel B: L2-resident quarter-slice gather + MFMA gate ----------------
// One launch = one phase = 8 groups (batch, quarter-lo). Each group pins to one XCD
// via (blockIdx & 7): 3.2 MB hot set per XCD L2. Two stream-ordered launches cover
// all 4 quarters WITHOUT concurrent working-set overlap (fix for round-5 regression).
__global__ __launch_bounds__(256, 4) void gated_spiral_quarter(
    const unsigned short* __restrict__ xb,
    const int* __restrict__ indices,
    const float* __restrict__ weight,
    const float* __restrict__ gate_w,
    const float* __restrict__ gate_b,
    float* __restrict__ out,
    int phase)
{
    __shared__ float spiral[TILE * PAD_Q];                 // 9216 B
    __shared__ unsigned short gbuf[4][2][CHUNK_SHORTS];    // 24576 B
    __shared__ int   idx_s[TILE * SEQ];                    // 3072 B
    __shared__ float w_s[TILE * SEQ];                      // 3072 B -> 39936 B, 4 blk/CU

    const int tid  = threadIdx.x;
    const int wave = tid >> 6;
    const int lane = tid & 63;

    const int g8    = blockIdx.x & 7;    // XCD affinity (round-robin heuristic)
    const int tile  = blockIdx.x >> 3;
    const int b     = g8 >> 1;
    const int q     = (g8 & 1) | (phase << 1);   // quarter 0..3
    const int node0 = tile * TILE;
    const unsigned short* xbb = xb + (size_t)b * N_NODES * CH;

    // ---- Phase 0 (wave-local): stage this wave's 16 nodes' indices + weights ----
    const int sbase = wave * 16 * SEQ;   // 192 entries/wave
    #pragma unroll
    for (int k3 = 0; k3 < 3; ++k3) {
        const int k = k3 * 64 + lane;
        int node = node0 + wave * 16 + k / SEQ;
        if (node >= N_NODES) node = N_NODES - 1;
        int t = __builtin_nontemporal_load(indices + (size_t)node * SEQ + (k % SEQ));
        t = t < 0 ? 0 : (t >= N_NODES ? N_NODES - 1 : t);
        idx_s[sbase + k] = t;
        w_s[sbase + k]   = __builtin_nontemporal_load(weight + (size_t)node * SEQ + (k % SEQ));
    }
    // same-wave LDS producer/consumer: ordered via lgkmcnt by the compiler

    // ---- Phase 1: per-wave double-buffered async quarter-slice gather + reduce ----
    {
        const int* idxw = idx_s + sbase;
        const float* ww = w_s + sbase;
        unsigned short* gw0 = &gbuf[wave][0][0];
        const int lrow = lane >> 2;          // 16 rows (64B each) per 1KB instr
        const int lco  = (lane & 3) * 8;     // bf16 elems within a 64B row slice

        // prologue: issue chunks 0 and 1 (3 x 1KB each)
        #pragma unroll
        for (int c0 = 0; c0 < 2; ++c0) {
            unsigned short* dst = gw0 + c0 * CHUNK_SHORTS;
            #pragma unroll
            for (int i = 0; i < CHUNK_INSTR; ++i) {
                const int rs = i * 16 + lrow;      // 0..47 = s*4 + n
                const int s = rs >> 2, n = rs & 3;
                const int row = idxw[(c0 * CNODES + n) * SEQ + s];
                gload_lds16b(xbb + (size_t)row * CH + q * QCH + lco, dst + i * 512);
            }
        }

        #pragma unroll
        for (int c = 0; c < NCHUNK; ++c) {
            if (c < NCHUNK - 1) asm volatile("s_waitcnt vmcnt(3)" ::: "memory");
            else                asm volatile("s_waitcnt vmcnt(0)" ::: "memory");
            __builtin_amdgcn_sched_barrier(0);

            unsigned short* bufp = gw0 + (c & 1) * CHUNK_SHORTS;
            const int nr = lane >> 4;            // node within chunk (0..3)
            const int cp = lane & 15;            // ch-pair (2 bf16) this lane owns
            const float* wp = ww + (c * CNODES + nr) * SEQ;
            float a0 = 0.f, a1 = 0.f;
            #pragma unroll
            for (int s = 0; s < SEQ; ++s) {
                const unsigned int u = *(const unsigned int*)(bufp + (s * 4 + nr) * QCH + cp * 2);
                const float ws = wp[s];
                a0 += ws * bflo(u); a1 += ws * bfhi(u);
            }
            const int r = wave * 16 + c * CNODES + nr;
            *(float2*)(spiral + r * PAD_Q + cp * 2) = make_float2(a0, a1);

            if (c + 2 < NCHUNK) {
                // drain ds_reads of this buffer before async loads overwrite it
                asm volatile("s_waitcnt lgkmcnt(0)" ::: "memory");
                __builtin_amdgcn_sched_barrier(0);
                #pragma unroll
                for (int i = 0; i < CHUNK_INSTR; ++i) {
                    const int rs = i * 16 + lrow;
                    const int s = rs >> 2, n = rs & 3;
                    const int row = idxw[((c + 2) * CNODES + n) * SEQ + s];
                    gload_lds16b(xbb + (size_t)row * CH + q * QCH + lco, bufp + i * 512);
                }
            }
        }
    }
    // no __syncthreads anywhere: all phases wave-local

    // ---- Phase 2: gate GEMM (sliced D: 16 nodes x 32 out-ch per wave) ----
    {
        const int m = lane & 15;
        const int quad = lane >> 4;

        int arow_node = node0 + wave * 16 + m;
        if (arow_node >= N_NODES) arow_node = N_NODES - 1;
        const unsigned short* ap = xbb + (size_t)arow_node * CH + quad * 8;

        // cacheable loads: sequential x rows are L3-resident; nontemporal here
        // forced HBM re-fetch in round 5 (FETCH 201->356 MB).
        bf16x8 afrag[4];
        #pragma unroll
        for (int kk = 0; kk < 4; ++kk)
            afrag[kk] = *(const bf16x8*)(ap + kk * 32);

        float gbv[2];
        #pragma unroll
        for (int t = 0; t < 2; ++t)
            gbv[t] = gate_b[q * QCH + t * 16 + m];

        #pragma unroll
        for (int t = 0; t < 2; ++t) {
            f32x4 c = {0.f, 0.f, 0.f, 0.f};
            const float* bp = gate_w + (size_t)(q * QCH + t * 16 + m) * CH + quad * 8;
            #pragma unroll
            for (int kk = 0; kk < 4; ++kk) {
                float4 lo = *(const float4*)(bp + kk * 32);
                float4 hi = *(const float4*)(bp + kk * 32 + 4);
                union { bf16x8 v; __hip_bfloat16 h[8]; } bf;
                bf.h[0] = __float2bfloat16(lo.x); bf.h[1] = __float2bfloat16(lo.y);
                bf.h[2] = __float2bfloat16(lo.z); bf.h[3] = __float2bfloat16(lo.w);
                bf.h[4] = __float2bfloat16(hi.x); bf.h[5] = __float2bfloat16(hi.y);
                bf.h[6] = __float2bfloat16(hi.z); bf.h[7] = __float2bfloat16(hi.w);
                c = __builtin_amdgcn_mfma_f32_16x16x32_bf16(afrag[kk], bf.v, c, 0, 0, 0);
            }
            #pragma unroll
            for (int reg = 0; reg < 4; ++reg) {
                const int r = wave * 16 + quad * 4 + reg;
                const int col = t * 16 + m;                    // out-ch within slice
                const float sp = spiral[r * PAD_Q + col];
                spiral[r * PAD_Q + col] = sp * (c[reg] + gbv[t]);
            }
        }
    }

    // ---- Phase 3: wave-local coalesced slice store (nontemporal) ----
    {
        #pragma unroll
        for (int p = 0; p < 2; ++p) {
            const int seg = p * 64 + lane;        // 128 float4-segments per wave
            const int r = seg >> 3;               // 0..15
            const int i8 = seg & 7;               // float4 index within 32-ch slice
            const int node = node0 + wave * 16 + r;
            if (node < N_NODES) {
                const float* sp = spiral + (wave * 16 + r) * PAD_Q + i8 * 4;
                f32x4 v = { sp[0], sp[1], sp[2], sp[3] };
                __builtin_nontemporal_store(v,
                    (f32x4*)(out + ((size_t)b * N_NODES + node) * CH + q * QCH + i8 * 4));
            }
        }
    }
}

// ---------------- Fallback: proven round-3 fp32 async kernel (ws too small) ----------------
#define NODES_PER_WAVE 16
#define FCHUNK_NODES 2
#define FCHUNK_FLOATS (FCHUNK_NODES * SEQ * CH)  // 3072 floats = 12 KB
#define FNCHUNK (NODES_PER_WAVE / FCHUNK_NODES)  // 8

__global__ __launch_bounds__(256, 1) void gated_spiral_async(
    const float* __restrict__ x,
    const int* __restrict__ indices,
    const float* __restrict__ weight,
    const float* __restrict__ gate_w,
    const float* __restrict__ gate_b,
    float* __restrict__ out)
{
    __shared__ float spiral[TILE * PAD_ROW];
    __shared__ float gbuf[4][2][FCHUNK_FLOATS];
    __shared__ int   idx_s[TILE * SEQ];
    __shared__ float w_s[TILE * SEQ];

    const int tid  = threadIdx.x;
    const int wave = tid >> 6;
    const int lane = tid & 63;
    const int b    = blockIdx.y;
    const int node0 = blockIdx.x * TILE;
    const float* xb = x + (size_t)b * N_NODES * CH;

    const int sbase = wave * NODES_PER_WAVE * SEQ;
    #pragma unroll
    for (int k3 = 0; k3 < 3; ++k3) {
        const int k = k3 * 64 + lane;
        int node = node0 + wave * NODES_PER_WAVE + k / SEQ;
        if (node >= N_NODES) node = N_NODES - 1;
        int t = indices[(size_t)node * SEQ + (k % SEQ)];
        t = t < 0 ? 0 : (t >= N_NODES ? N_NODES - 1 : t);
        idx_s[sbase + k] = t;
        w_s[sbase + k]   = weight[(size_t)node * SEQ + (k % SEQ)];
    }

    {
        const int n  = lane >> 5;
        const int co = (lane & 31) * 4;
        const int* idxw = idx_s + sbase;
        const float* ww = w_s + sbase;
        float* gb0 = &gbuf[wave][0][0];

        #pragma unroll
        for (int c0 = 0; c0 < 2; ++c0) {
            const int* ix = idxw + c0 * FCHUNK_NODES * SEQ;
            float* dst = gb0 + c0 * FCHUNK_FLOATS;
            #pragma unroll
            for (int s = 0; s < SEQ; ++s) {
                const int row = ix[n * SEQ + s];
                gload_lds16f(xb + (size_t)row * CH + co, dst + s * (FCHUNK_NODES * CH));
            }
        }

        #pragma unroll
        for (int c = 0; c < FNCHUNK; ++c) {
            if (c < FNCHUNK - 1) asm volatile("s_waitcnt vmcnt(12)" ::: "memory");
            else                 asm volatile("s_waitcnt vmcnt(0)"  ::: "memory");
            __builtin_amdgcn_sched_barrier(0);

            float* cur = gb0 + (c & 1) * FCHUNK_FLOATS;
            const float* wp = ww + c * FCHUNK_NODES * SEQ + n * SEQ;
            float a0 = 0.f, a1 = 0.f, a2 = 0.f, a3 = 0.f;
            #pragma unroll
            for (int s = 0; s < SEQ; ++s) {
                const float4 d = *(const float4*)(cur + (s * FCHUNK_NODES + n) * CH + co);
                const float ws = wp[s];
                a0 += ws * d.x; a1 += ws * d.y; a2 += ws * d.z; a3 += ws * d.w;
            }
            const int r = wave * NODES_PER_WAVE + c * FCHUNK_NODES + n;
            *(float4*)(spiral + r * PAD_ROW + co) = make_float4(a0, a1, a2, a3);

            if (c + 2 < FNCHUNK) {
                asm volatile("s_waitcnt lgkmcnt(0)" ::: "memory");
                __builtin_amdgcn_sched_barrier(0);
                const int* ix = idxw + (c + 2) * FCHUNK_NODES * SEQ;
                #pragma unroll
                for (int s = 0; s < SEQ; ++s) {
                    const int row = ix[n * SEQ + s];
                    gload_lds16f(xb + (size_t)row * CH + co, cur + s * (FCHUNK_NODES * CH));
                }
            }
        }
    }

    {
        const int m = lane & 15;
        const int quad = lane >> 4;

        int arow_node = node0 + wave * 16 + m;
        if (arow_node >= N_NODES) arow_node = N_NODES - 1;
        const float* ap = xb + (size_t)arow_node * CH + quad * 8;

        bf16x8 afrag[4];
        #pragma unroll
        for (int kk = 0; kk < 4; ++kk) {
            float4 lo = *(const float4*)(ap + kk * 32);
            float4 hi = *(const float4*)(ap + kk * 32 + 4);
            union { bf16x8 v; __hip_bfloat16 h[8]; } af;
            af.h[0] = __float2bfloat16(lo.x); af.h[1] = __float2bfloat16(lo.y);
            af.h[2] = __float2bfloat16(lo.z); af.h[3] = __float2bfloat16(lo.w);
            af.h[4] = __float2bfloat16(hi.x); af.h[5] = __float2bfloat16(hi.y);
            af.h[6] = __float2bfloat16(hi.z); af.h[7] = __float2bfloat16(hi.w);
            afrag[kk] = af.v;
        }

        float gbv[8];
        #pragma unroll
        for (int t = 0; t < 8; ++t)
            gbv[t] = gate_b[t * 16 + m];

        #pragma unroll
        for (int t = 0; t < 8; ++t) {
            f32x4 c = {0.f, 0.f, 0.f, 0.f};
            const float* bp = gate_w + (size_t)(t * 16 + m) * CH + quad * 8;
            #pragma unroll
            for (int kk = 0; kk < 4; ++kk) {
                float4 lo = *(const float4*)(bp + kk * 32);
                float4 hi = *(const float4*)(bp + kk * 32 + 4);
                union { bf16x8 v; __hip_bfloat16 h[8]; } bf;
                bf.h[0] = __float2bfloat16(lo.x); bf.h[1] = __float2bfloat16(lo.y);
                bf.h[2] = __float2bfloat16(lo.z); bf.h[3] = __float2bfloat16(lo.w);
                bf.h[4] = __float2bfloat16(hi.x); bf.h[5] = __float2bfloat16(hi.y);
                bf.h[6] = __float2bfloat16(hi.z); bf.h[7] = __float2bfloat16(hi.w);
                c = __builtin_amdgcn_mfma_f32_16x16x32_bf16(afrag[kk], bf.v, c, 0, 0, 0);
            }
            #pragma unroll
            for (int reg = 0; reg < 4; ++reg) {
                const int r = wave * 16 + quad * 4 + reg;
                const int col = t * 16 + m;
                const float sp = spiral[r * PAD_ROW + col];
                spiral[r * PAD_ROW + col] = sp * (c[reg] + gbv[t]);
            }
        }
    }

    {
        #pragma unroll
        for (int p = 0; p < 8; ++p) {
            const int seg = p * 64 + lane;
            const int r = seg >> 5;
            const int c4 = (seg & 31) * 4;
            const int node = node0 + wave * 16 + r;
            if (node < N_NODES) {
                const float* sp = spiral + (wave * 16 + r) * PAD_ROW + c4;
                f32x4 v = { sp[0], sp[1], sp[2], sp[3] };
                __builtin_nontemporal_store(v, (f32x4*)(out + ((size_t)b * N_NODES + node) * CH + c4));
            }
        }
    }
}

extern "C" void kernel_launch(void* const* d_in, const int* in_sizes, int n_in,
                              void* d_out, int out_size, void* d_ws, size_t ws_size,
                              hipStream_t stream) {
    const float* x       = (const float*)d_in[0];
    const int*   indices = (const int*)d_in[1];
    const float* weight  = (const float*)d_in[2];
    const float* gate_w  = (const float*)d_in[3];
    const float* gate_b  = (const float*)d_in[4];
    float*       out     = (float*)d_out;

    const size_t x_bf_bytes = (size_t)BS * N_NODES * CH * 2;   // 51,200,000

    if (ws_size >= x_bf_bytes) {
        unsigned short* xbuf = (unsigned short*)d_ws;
        const size_t n8 = (size_t)BS * N_NODES * CH / 8;       // 3,200,000
        convert_kernel<<<dim3((unsigned)((n8 + 255) / 256)), dim3(256), 0, stream>>>(x, xbuf);
        // two stream-ordered phases: per phase, one 3.2 MB (batch, quarter) slice per XCD
        gated_spiral_quarter<<<dim3(NTILES * 8), dim3(256), 0, stream>>>(
            xbuf, indices, weight, gate_w, gate_b, out, 0);
        gated_spiral_quarter<<<dim3(NTILES * 8), dim3(256), 0, stream>>>(
            xbuf, indices, weight, gate_w, gate_b, out, 1);
    } else {
        dim3 grid(NTILES, BS);
        gated_spiral_async<<<grid, dim3(256), 0, stream>>>(
            x, indices, weight, gate_w, gate_b, out);
    }
}